// Round 1
// baseline (412.177 us; speedup 1.0000x reference)
//
#include <hip/hip_runtime.h>
#include <math.h>

#define B 32
#define T 2048
#define D 1024
#define MEM 64
#define HID 512
#define NCH 16
#define TCH (T / NCH) /* 128 */

// workspace layout in floats
#define OFF_PART 0                    /* NCH*B*D = 524288 */
#define OFF_XM (NCH * B * D)          /* 524288 */
#define OFF_XP (OFF_XM + B * D)       /* 557056 */
#define OFF_H (OFF_XP + B * D)        /* 589824 */
#define OFF_LG (OFF_H + B * HID)      /* 606208 */
#define OFF_XPN (OFF_LG + B * MEM)    /* 608256 */
#define OFF_SIMS (OFF_XPN + B)        /* 608288 */

__device__ inline float waveReduceSum(float v) {
#pragma unroll
  for (int m = 32; m; m >>= 1) v += __shfl_xor(v, m, 64);
  return v;
}

// ---- 1. partial sums of x over T-chunks: part[ch][b][d] ----
__global__ __launch_bounds__(256) void k_partial(const float* __restrict__ x,
                                                 float* __restrict__ part) {
  const int ch = blockIdx.x, b = blockIdx.y, d4 = threadIdx.x;
  const float4* xv =
      (const float4*)x + (((size_t)(b * T + ch * TCH) * D) >> 2) + d4;
  float4 acc = make_float4(0.f, 0.f, 0.f, 0.f);
#pragma unroll 4
  for (int t = 0; t < TCH; ++t) {
    float4 v = xv[(size_t)t * (D >> 2)];
    acc.x += v.x;
    acc.y += v.y;
    acc.z += v.z;
    acc.w += v.w;
  }
  ((float4*)(part + (size_t)(ch * B + b) * D))[d4] = acc;
}

// ---- 2. reduce partials -> mean xm[b][d] ----
__global__ __launch_bounds__(256) void k_mean(const float* __restrict__ part,
                                              float* __restrict__ xm) {
  const int b = blockIdx.x, d4 = threadIdx.x;
  float4 acc = make_float4(0.f, 0.f, 0.f, 0.f);
  for (int ch = 0; ch < NCH; ++ch) {
    float4 v = ((const float4*)(part + (size_t)(ch * B + b) * D))[d4];
    acc.x += v.x;
    acc.y += v.y;
    acc.z += v.z;
    acc.w += v.w;
  }
  const float s = 1.0f / (float)T;
  acc.x *= s;
  acc.y *= s;
  acc.z *= s;
  acc.w *= s;
  ((float4*)(xm + (size_t)b * D))[d4] = acc;
}

// ---- 3. xp[b][e] = dot(xm[b], xa_w[e]) + xa_b[e]  (wave per output) ----
__global__ __launch_bounds__(256) void k_xp(const float* __restrict__ xm,
                                            const float* __restrict__ w,
                                            const float* __restrict__ bias,
                                            float* __restrict__ xp) {
  const int tid = threadIdx.x, lane = tid & 63, wv = tid >> 6;
  const int p = blockIdx.x * 4 + wv;
  const int b = p >> 10, e = p & 1023;
  const float4* a4 = (const float4*)(xm + (size_t)b * D);
  const float4* w4 = (const float4*)(w + (size_t)e * D);
  float acc = 0.f;
#pragma unroll
  for (int j = 0; j < 4; ++j) {
    float4 av = a4[j * 64 + lane];
    float4 wvv = w4[j * 64 + lane];
    acc += av.x * wvv.x + av.y * wvv.y + av.z * wvv.z + av.w * wvv.w;
  }
  acc = waveReduceSum(acc);
  if (lane == 0) xp[(size_t)b * D + e] = acc + bias[e];
}

// ---- 4. per-b: ||xp||, cosine sims vs mkey0/1 ----
__global__ __launch_bounds__(256) void k_stats(const float* __restrict__ xp,
                                               const float* __restrict__ mk0,
                                               const float* __restrict__ mk1,
                                               float* __restrict__ xpn,
                                               float* __restrict__ sims) {
  const int b = blockIdx.x, tid = threadIdx.x, lane = tid & 63, wv = tid >> 6;
  float xx = 0.f, d0 = 0.f, d1 = 0.f, n0 = 0.f, n1 = 0.f;
#pragma unroll
  for (int k = 0; k < 4; ++k) {
    int d = tid + k * 256;
    float v = xp[(size_t)b * D + d];
    float a = mk0[d];
    float c = mk1[d];
    xx += v * v;
    d0 += v * a;
    d1 += v * c;
    n0 += a * a;
    n1 += c * c;
  }
  xx = waveReduceSum(xx);
  d0 = waveReduceSum(d0);
  d1 = waveReduceSum(d1);
  n0 = waveReduceSum(n0);
  n1 = waveReduceSum(n1);
  __shared__ float s[4][5];
  if (lane == 0) {
    s[wv][0] = xx;
    s[wv][1] = d0;
    s[wv][2] = d1;
    s[wv][3] = n0;
    s[wv][4] = n1;
  }
  __syncthreads();
  if (tid == 0) {
    float X = 0, A = 0, C = 0, N0 = 0, N1 = 0;
    for (int i = 0; i < 4; ++i) {
      X += s[i][0];
      A += s[i][1];
      C += s[i][2];
      N0 += s[i][3];
      N1 += s[i][4];
    }
    float xn = sqrtf(X);
    xpn[b] = xn;
    sims[b * 2 + 0] = A / fmaxf(xn * sqrtf(N0), 1e-8f);
    sims[b * 2 + 1] = C / fmaxf(xn * sqrtf(N1), 1e-8f);
  }
}

// ---- 5. change-detector scalar output (single wave) ----
__global__ void k_scalar(const float* __restrict__ sims,
                         const float* __restrict__ thr,
                         float* __restrict__ out) {
  int lane = threadIdx.x;
  int bc = lane < B ? lane : (B - 1);
  // argmax with first-on-tie: best=1 only if sims1 strictly greater
  int best = (sims[bc * 2 + 1] > sims[bc * 2 + 0]) ? 1 : 0;
  int prev = __shfl_up(best, 1, 64);
  if (lane < B) {
    int changed = (lane == 0) ? 1 : (best != prev);
    float cs = changed ? 1.0f : 0.0f;
    out[lane] = (cs > thr[0]) ? 1.0f : 0.0f;
  }
}

// ---- 6. attention logits: normalized dot / sqrt(D) ----
__global__ __launch_bounds__(256) void k_att(const float* __restrict__ xp,
                                             const float* __restrict__ key,
                                             const float* __restrict__ xpn,
                                             float* __restrict__ logit) {
  const int tid = threadIdx.x, lane = tid & 63, wv = tid >> 6;
  const int p = blockIdx.x * 4 + wv;
  const int b = p >> 6, m = p & 63;
  const float4* a4 = (const float4*)(xp + (size_t)b * D);
  const float4* k4 = (const float4*)(key + (size_t)m * D);
  float dot = 0.f, k2 = 0.f;
#pragma unroll
  for (int j = 0; j < 4; ++j) {
    float4 av = a4[j * 64 + lane];
    float4 kv = k4[j * 64 + lane];
    dot += av.x * kv.x + av.y * kv.y + av.z * kv.z + av.w * kv.w;
    k2 += kv.x * kv.x + kv.y * kv.y + kv.z * kv.z + kv.w * kv.w;
  }
  dot = waveReduceSum(dot);
  k2 = waveReduceSum(k2);
  if (lane == 0) {
    float denom =
        fmaxf(xpn[b], 1e-12f) * fmaxf(sqrtf(k2), 1e-12f) * 32.0f; // sqrt(D)=32
    logit[b * MEM + m] = dot / denom;
  }
}

// ---- 7. MLP layer 1 + SiLU: h[b][j] ----
__global__ __launch_bounds__(256) void k_mlp1(const float* __restrict__ xp,
                                              const float* __restrict__ w1,
                                              const float* __restrict__ b1,
                                              float* __restrict__ h) {
  const int tid = threadIdx.x, lane = tid & 63, wv = tid >> 6;
  const int p = blockIdx.x * 4 + wv;
  const int b = p >> 9, j = p & 511;
  const float4* a4 = (const float4*)(xp + (size_t)b * D);
  const float4* w4 = (const float4*)(w1 + (size_t)j * D);
  float acc = 0.f;
#pragma unroll
  for (int q = 0; q < 4; ++q) {
    float4 av = a4[q * 64 + lane];
    float4 wvv = w4[q * 64 + lane];
    acc += av.x * wvv.x + av.y * wvv.y + av.z * wvv.z + av.w * wvv.w;
  }
  acc = waveReduceSum(acc);
  if (lane == 0) {
    float z = acc + b1[j];
    h[(size_t)b * HID + j] = z / (1.0f + expf(-z)); // silu
  }
}

// ---- 8. softmax(64) + att@val, h@w2, concat gate ----
__global__ __launch_bounds__(256) void k_final(
    const float* __restrict__ h, const float* __restrict__ w2,
    const float* __restrict__ b2, const float* __restrict__ logit,
    const float* __restrict__ val, const float* __restrict__ cw,
    const float* __restrict__ cb, float* __restrict__ out) {
  const int b = blockIdx.x, tid = threadIdx.x, lane = tid & 63, wv = tid >> 6;
  __shared__ float s_red[4];
  __shared__ float s_mem;
  float acc = h[(size_t)b * HID + tid] * w2[tid] +
              h[(size_t)b * HID + 256 + tid] * w2[256 + tid];
  acc = waveReduceSum(acc);
  if (lane == 0) s_red[wv] = acc;
  if (wv == 0) { // wave 0 = exactly 64 lanes = MEM
    float l = logit[b * MEM + lane];
    float mx = l;
#pragma unroll
    for (int m = 32; m; m >>= 1) mx = fmaxf(mx, __shfl_xor(mx, m, 64));
    float ex = expf(l - mx);
    float sm = waveReduceSum(ex);
    float mv = waveReduceSum((ex / sm) * val[lane]);
    if (lane == 0) s_mem = mv;
  }
  __syncthreads();
  if (tid == 0) {
    float mlp = s_red[0] + s_red[1] + s_red[2] + s_red[3] + b2[0];
    out[B + b] = cw[0] * s_mem + cw[1] * mlp + cb[0];
  }
}

extern "C" void kernel_launch(void* const* d_in, const int* in_sizes, int n_in,
                              void* d_out, int out_size, void* d_ws,
                              size_t ws_size, hipStream_t stream) {
  const float* x = (const float*)d_in[0];
  const float* mk0 = (const float*)d_in[1];
  const float* mk1 = (const float*)d_in[2];
  const float* key = (const float*)d_in[3];
  const float* val = (const float*)d_in[4];
  const float* w1 = (const float*)d_in[5];
  const float* b1 = (const float*)d_in[6];
  const float* w2 = (const float*)d_in[7];
  const float* b2 = (const float*)d_in[8];
  const float* cw = (const float*)d_in[9];
  const float* cb = (const float*)d_in[10];
  const float* xaw = (const float*)d_in[11];
  const float* xab = (const float*)d_in[12];
  const float* thr = (const float*)d_in[13];
  float* out = (float*)d_out;
  float* ws = (float*)d_ws;

  float* part = ws + OFF_PART;
  float* xm = ws + OFF_XM;
  float* xp = ws + OFF_XP;
  float* h = ws + OFF_H;
  float* lg = ws + OFF_LG;
  float* xpn = ws + OFF_XPN;
  float* sims = ws + OFF_SIMS;

  k_partial<<<dim3(NCH, B), 256, 0, stream>>>(x, part);
  k_mean<<<B, 256, 0, stream>>>(part, xm);
  k_xp<<<(B * D) / 4, 256, 0, stream>>>(xm, xaw, xab, xp);
  k_stats<<<B, 256, 0, stream>>>(xp, mk0, mk1, xpn, sims);
  k_scalar<<<1, 64, 0, stream>>>(sims, thr, out);
  k_att<<<(B * MEM) / 4, 256, 0, stream>>>(xp, key, xpn, lg);
  k_mlp1<<<(B * HID) / 4, 256, 0, stream>>>(xp, w1, b1, h);
  k_final<<<B, 256, 0, stream>>>(h, w2, b2, lg, val, cw, cb, out);
}

// Round 2
// 411.800 us; speedup vs baseline: 1.0009x; 1.0009x over previous
//
#include <hip/hip_runtime.h>
#include <math.h>

#define B 32
#define T 2048
#define D 1024
#define MEM 64
#define HID 512
#define NCH 64
#define TCH (T / NCH) /* 32 */

// workspace layout in floats
#define OFF_PART 0                    /* NCH*B*D = 2097152 */
#define OFF_XM (NCH * B * D)
#define OFF_XP (OFF_XM + B * D)
#define OFF_H (OFF_XP + B * D)
#define OFF_LG (OFF_H + B * HID)
#define OFF_XPN (OFF_LG + B * MEM)
#define OFF_SIMS (OFF_XPN + B)

__device__ inline float waveReduceSum(float v) {
#pragma unroll
  for (int m = 32; m; m >>= 1) v += __shfl_xor(v, m, 64);
  return v;
}

// ---- 1. partial sums of x over T-chunks: part[ch][b][d] ----
// 2048 blocks = 8 blocks/CU = 32 waves/CU (max occupancy); each thread does
// 32 fully-coalesced float4 loads, unroll 8 -> 8 loads in flight.
__global__ __launch_bounds__(256) void k_partial(const float* __restrict__ x,
                                                 float* __restrict__ part) {
  const int ch = blockIdx.x, b = blockIdx.y, d4 = threadIdx.x;
  const float4* xv =
      (const float4*)x + (((size_t)(b * T + ch * TCH) * D) >> 2) + d4;
  float4 acc = make_float4(0.f, 0.f, 0.f, 0.f);
#pragma unroll 8
  for (int t = 0; t < TCH; ++t) {
    float4 v = xv[(size_t)t * (D >> 2)];
    acc.x += v.x;
    acc.y += v.y;
    acc.z += v.z;
    acc.w += v.w;
  }
  ((float4*)(part + (size_t)(ch * B + b) * D))[d4] = acc;
}

// ---- 2. reduce partials -> mean xm[b][d] ----
__global__ __launch_bounds__(256) void k_mean(const float* __restrict__ part,
                                              float* __restrict__ xm) {
  const int b = blockIdx.x, d4 = threadIdx.x;
  float4 acc = make_float4(0.f, 0.f, 0.f, 0.f);
#pragma unroll 8
  for (int ch = 0; ch < NCH; ++ch) {
    float4 v = ((const float4*)(part + (size_t)(ch * B + b) * D))[d4];
    acc.x += v.x;
    acc.y += v.y;
    acc.z += v.z;
    acc.w += v.w;
  }
  const float s = 1.0f / (float)T;
  acc.x *= s;
  acc.y *= s;
  acc.z *= s;
  acc.w *= s;
  ((float4*)(xm + (size_t)b * D))[d4] = acc;
}

// ---- 3. xp[b][e] = dot(xm[b], xa_w[e]) + xa_b[e]  (wave per output) ----
__global__ __launch_bounds__(256) void k_xp(const float* __restrict__ xm,
                                            const float* __restrict__ w,
                                            const float* __restrict__ bias,
                                            float* __restrict__ xp) {
  const int tid = threadIdx.x, lane = tid & 63, wv = tid >> 6;
  const int p = blockIdx.x * 4 + wv;
  const int b = p >> 10, e = p & 1023;
  const float4* a4 = (const float4*)(xm + (size_t)b * D);
  const float4* w4 = (const float4*)(w + (size_t)e * D);
  float acc = 0.f;
#pragma unroll
  for (int j = 0; j < 4; ++j) {
    float4 av = a4[j * 64 + lane];
    float4 wvv = w4[j * 64 + lane];
    acc += av.x * wvv.x + av.y * wvv.y + av.z * wvv.z + av.w * wvv.w;
  }
  acc = waveReduceSum(acc);
  if (lane == 0) xp[(size_t)b * D + e] = acc + bias[e];
}

// ---- 4. per-b: ||xp||, cosine sims vs mkey0/1 ----
__global__ __launch_bounds__(256) void k_stats(const float* __restrict__ xp,
                                               const float* __restrict__ mk0,
                                               const float* __restrict__ mk1,
                                               float* __restrict__ xpn,
                                               float* __restrict__ sims) {
  const int b = blockIdx.x, tid = threadIdx.x, lane = tid & 63, wv = tid >> 6;
  float xx = 0.f, d0 = 0.f, d1 = 0.f, n0 = 0.f, n1 = 0.f;
#pragma unroll
  for (int k = 0; k < 4; ++k) {
    int d = tid + k * 256;
    float v = xp[(size_t)b * D + d];
    float a = mk0[d];
    float c = mk1[d];
    xx += v * v;
    d0 += v * a;
    d1 += v * c;
    n0 += a * a;
    n1 += c * c;
  }
  xx = waveReduceSum(xx);
  d0 = waveReduceSum(d0);
  d1 = waveReduceSum(d1);
  n0 = waveReduceSum(n0);
  n1 = waveReduceSum(n1);
  __shared__ float s[4][5];
  if (lane == 0) {
    s[wv][0] = xx;
    s[wv][1] = d0;
    s[wv][2] = d1;
    s[wv][3] = n0;
    s[wv][4] = n1;
  }
  __syncthreads();
  if (tid == 0) {
    float X = 0, A = 0, C = 0, N0 = 0, N1 = 0;
    for (int i = 0; i < 4; ++i) {
      X += s[i][0];
      A += s[i][1];
      C += s[i][2];
      N0 += s[i][3];
      N1 += s[i][4];
    }
    float xn = sqrtf(X);
    xpn[b] = xn;
    sims[b * 2 + 0] = A / fmaxf(xn * sqrtf(N0), 1e-8f);
    sims[b * 2 + 1] = C / fmaxf(xn * sqrtf(N1), 1e-8f);
  }
}

// ---- 5. fused attention logits (blocks 0..511) + MLP1/SiLU (blocks 512..4607) ----
__global__ __launch_bounds__(256) void k_att_mlp1(
    const float* __restrict__ xp, const float* __restrict__ key,
    const float* __restrict__ xpn, float* __restrict__ logit,
    const float* __restrict__ w1, const float* __restrict__ b1,
    float* __restrict__ h) {
  const int tid = threadIdx.x, lane = tid & 63, wv = tid >> 6;
  if (blockIdx.x < (B * MEM) / 4) {
    // attention logits: wave per (b,m)
    const int p = blockIdx.x * 4 + wv;
    const int b = p >> 6, m = p & 63;
    const float4* a4 = (const float4*)(xp + (size_t)b * D);
    const float4* k4 = (const float4*)(key + (size_t)m * D);
    float dot = 0.f, k2 = 0.f;
#pragma unroll
    for (int j = 0; j < 4; ++j) {
      float4 av = a4[j * 64 + lane];
      float4 kv = k4[j * 64 + lane];
      dot += av.x * kv.x + av.y * kv.y + av.z * kv.z + av.w * kv.w;
      k2 += kv.x * kv.x + kv.y * kv.y + kv.z * kv.z + kv.w * kv.w;
    }
    dot = waveReduceSum(dot);
    k2 = waveReduceSum(k2);
    if (lane == 0) {
      float denom =
          fmaxf(xpn[b], 1e-12f) * fmaxf(sqrtf(k2), 1e-12f) * 32.0f; // sqrt(D)
      logit[b * MEM + m] = dot / denom;
    }
  } else {
    // MLP layer 1 + SiLU: wave per (b,j)
    const int p = (blockIdx.x - (B * MEM) / 4) * 4 + wv;
    const int b = p >> 9, j = p & 511;
    const float4* a4 = (const float4*)(xp + (size_t)b * D);
    const float4* w4 = (const float4*)(w1 + (size_t)j * D);
    float acc = 0.f;
#pragma unroll
    for (int q = 0; q < 4; ++q) {
      float4 av = a4[q * 64 + lane];
      float4 wvv = w4[q * 64 + lane];
      acc += av.x * wvv.x + av.y * wvv.y + av.z * wvv.z + av.w * wvv.w;
    }
    acc = waveReduceSum(acc);
    if (lane == 0) {
      float z = acc + b1[j];
      h[(size_t)b * HID + j] = z / (1.0f + expf(-z)); // silu
    }
  }
}

// ---- 6. softmax(64) + att@val, h@w2, concat gate, + change-detector scalar ----
__global__ __launch_bounds__(256) void k_final(
    const float* __restrict__ h, const float* __restrict__ w2,
    const float* __restrict__ b2, const float* __restrict__ logit,
    const float* __restrict__ val, const float* __restrict__ cw,
    const float* __restrict__ cb, const float* __restrict__ sims,
    const float* __restrict__ thr, float* __restrict__ out) {
  const int b = blockIdx.x, tid = threadIdx.x, lane = tid & 63, wv = tid >> 6;
  __shared__ float s_red[4];
  __shared__ float s_mem;
  float acc = h[(size_t)b * HID + tid] * w2[tid] +
              h[(size_t)b * HID + 256 + tid] * w2[256 + tid];
  acc = waveReduceSum(acc);
  if (lane == 0) s_red[wv] = acc;
  if (wv == 0) { // wave 0 = exactly 64 lanes = MEM
    float l = logit[b * MEM + lane];
    float mx = l;
#pragma unroll
    for (int m = 32; m; m >>= 1) mx = fmaxf(mx, __shfl_xor(mx, m, 64));
    float ex = expf(l - mx);
    float sm = waveReduceSum(ex);
    float mv = waveReduceSum((ex / sm) * val[lane]);
    if (lane == 0) s_mem = mv;
  }
  __syncthreads();
  if (tid == 0) {
    float mlp = s_red[0] + s_red[1] + s_red[2] + s_red[3] + b2[0];
    out[B + b] = cw[0] * s_mem + cw[1] * mlp + cb[0];
    // change-detector scalar (argmax first-on-tie => strict >)
    int best = (sims[b * 2 + 1] > sims[b * 2 + 0]) ? 1 : 0;
    int changed;
    if (b == 0) {
      changed = 1;
    } else {
      int prev = (sims[(b - 1) * 2 + 1] > sims[(b - 1) * 2 + 0]) ? 1 : 0;
      changed = (best != prev);
    }
    out[b] = ((changed ? 1.0f : 0.0f) > thr[0]) ? 1.0f : 0.0f;
  }
}

extern "C" void kernel_launch(void* const* d_in, const int* in_sizes, int n_in,
                              void* d_out, int out_size, void* d_ws,
                              size_t ws_size, hipStream_t stream) {
  const float* x = (const float*)d_in[0];
  const float* mk0 = (const float*)d_in[1];
  const float* mk1 = (const float*)d_in[2];
  const float* key = (const float*)d_in[3];
  const float* val = (const float*)d_in[4];
  const float* w1 = (const float*)d_in[5];
  const float* b1 = (const float*)d_in[6];
  const float* w2 = (const float*)d_in[7];
  const float* b2 = (const float*)d_in[8];
  const float* cw = (const float*)d_in[9];
  const float* cb = (const float*)d_in[10];
  const float* xaw = (const float*)d_in[11];
  const float* xab = (const float*)d_in[12];
  const float* thr = (const float*)d_in[13];
  float* out = (float*)d_out;
  float* ws = (float*)d_ws;

  float* part = ws + OFF_PART;
  float* xm = ws + OFF_XM;
  float* xp = ws + OFF_XP;
  float* h = ws + OFF_H;
  float* lg = ws + OFF_LG;
  float* xpn = ws + OFF_XPN;
  float* sims = ws + OFF_SIMS;

  k_partial<<<dim3(NCH, B), 256, 0, stream>>>(x, part);
  k_mean<<<B, 256, 0, stream>>>(part, xm);
  k_xp<<<(B * D) / 4, 256, 0, stream>>>(xm, xaw, xab, xp);
  k_stats<<<B, 256, 0, stream>>>(xp, mk0, mk1, xpn, sims);
  k_att_mlp1<<<(B * MEM) / 4 + (B * HID) / 4, 256, 0, stream>>>(
      xp, key, xpn, lg, w1, b1, h);
  k_final<<<B, 256, 0, stream>>>(h, w2, b2, lg, val, cw, cb, sims, thr, out);
}

// Round 3
// 400.824 us; speedup vs baseline: 1.0283x; 1.0274x over previous
//
#include <hip/hip_runtime.h>
#include <math.h>

#define B 32
#define T 2048
#define D 1024
#define MEM 64
#define HID 512
#define NCH 16
#define TCH (T / NCH) /* 128 */

// workspace layout in floats
#define OFF_PART 0                 /* NCH*B*D = 524288 */
#define OFF_XM (NCH * B * D)
#define OFF_XP (OFF_XM + B * D)
#define OFF_H (OFF_XP + B * D)
#define OFF_LG (OFF_H + B * HID)
#define OFF_SIMS (OFF_LG + B * MEM)

#define ATT_BLKS ((B * MEM) / 4)   /* 512 */
#define MLP_BLKS ((B * HID) / 4)   /* 4096 */
#define STATS_BLKS (B / 4)         /* 8 */

__device__ inline float waveReduceSum(float v) {
#pragma unroll
  for (int m = 32; m; m >>= 1) v += __shfl_xor(v, m, 64);
  return v;
}

// ---- 1. partial sums of x over T-chunks: part[ch][b][d] ----
// 512 blocks = 8 waves/CU; unroll 8 -> 8 float4 loads in flight/thread.
// In-flight/CU = 8 waves * 8 * 64 * 16B = 64 KB >> 9 KB needed at 24.6 GB/s/CU
// => HBM-BW-bound. 256 MiB read + 2 MiB write.
__global__ __launch_bounds__(256) void k_partial(const float* __restrict__ x,
                                                 float* __restrict__ part) {
  const int ch = blockIdx.x, b = blockIdx.y, d4 = threadIdx.x;
  const float4* xv =
      (const float4*)x + (((size_t)(b * T + ch * TCH) * D) >> 2) + d4;
  float4 acc = make_float4(0.f, 0.f, 0.f, 0.f);
#pragma unroll 8
  for (int t = 0; t < TCH; ++t) {
    float4 v = xv[(size_t)t * (D >> 2)];
    acc.x += v.x;
    acc.y += v.y;
    acc.z += v.z;
    acc.w += v.w;
  }
  ((float4*)(part + (size_t)(ch * B + b) * D))[d4] = acc;
}

// ---- 2. reduce partials -> mean xm[b][d] ----
__global__ __launch_bounds__(256) void k_mean(const float* __restrict__ part,
                                              float* __restrict__ xm) {
  const int b = blockIdx.x, d4 = threadIdx.x;
  float4 acc = make_float4(0.f, 0.f, 0.f, 0.f);
#pragma unroll 8
  for (int ch = 0; ch < NCH; ++ch) {
    float4 v = ((const float4*)(part + (size_t)(ch * B + b) * D))[d4];
    acc.x += v.x;
    acc.y += v.y;
    acc.z += v.z;
    acc.w += v.w;
  }
  const float s = 1.0f / (float)T;
  acc.x *= s;
  acc.y *= s;
  acc.z *= s;
  acc.w *= s;
  ((float4*)(xm + (size_t)b * D))[d4] = acc;
}

// ---- 3. xp[b][e] = dot(xm[b], xa_w[e]) + xa_b[e]  (wave per output) ----
__global__ __launch_bounds__(256) void k_xp(const float* __restrict__ xm,
                                            const float* __restrict__ w,
                                            const float* __restrict__ bias,
                                            float* __restrict__ xp) {
  const int tid = threadIdx.x, lane = tid & 63, wv = tid >> 6;
  const int p = blockIdx.x * 4 + wv;
  const int b = p >> 10, e = p & 1023;
  const float4* a4 = (const float4*)(xm + (size_t)b * D);
  const float4* w4 = (const float4*)(w + (size_t)e * D);
  float acc = 0.f;
#pragma unroll
  for (int j = 0; j < 4; ++j) {
    float4 av = a4[j * 64 + lane];
    float4 wvv = w4[j * 64 + lane];
    acc += av.x * wvv.x + av.y * wvv.y + av.z * wvv.z + av.w * wvv.w;
  }
  acc = waveReduceSum(acc);
  if (lane == 0) xp[(size_t)b * D + e] = acc + bias[e];
}

// ---- 4. fused: att logits [0,512) + MLP1/SiLU [512,4608) + cos-sims [4608,4616) ----
__global__ __launch_bounds__(256) void k_fused(
    const float* __restrict__ xp, const float* __restrict__ key,
    float* __restrict__ logit, const float* __restrict__ w1,
    const float* __restrict__ b1, float* __restrict__ h,
    const float* __restrict__ mk0, const float* __restrict__ mk1,
    float* __restrict__ sims) {
  const int tid = threadIdx.x, lane = tid & 63, wv = tid >> 6;
  if (blockIdx.x < ATT_BLKS) {
    // attention logits: wave per (b,m); ||xp|| computed inline (row already loaded)
    const int p = blockIdx.x * 4 + wv;
    const int b = p >> 6, m = p & 63;
    const float4* a4 = (const float4*)(xp + (size_t)b * D);
    const float4* k4 = (const float4*)(key + (size_t)m * D);
    float dot = 0.f, k2 = 0.f, x2 = 0.f;
#pragma unroll
    for (int j = 0; j < 4; ++j) {
      float4 av = a4[j * 64 + lane];
      float4 kv = k4[j * 64 + lane];
      dot += av.x * kv.x + av.y * kv.y + av.z * kv.z + av.w * kv.w;
      k2 += kv.x * kv.x + kv.y * kv.y + kv.z * kv.z + kv.w * kv.w;
      x2 += av.x * av.x + av.y * av.y + av.z * av.z + av.w * av.w;
    }
    dot = waveReduceSum(dot);
    k2 = waveReduceSum(k2);
    x2 = waveReduceSum(x2);
    if (lane == 0) {
      float denom =
          fmaxf(sqrtf(x2), 1e-12f) * fmaxf(sqrtf(k2), 1e-12f) * 32.0f;
      logit[b * MEM + m] = dot / denom;
    }
  } else if (blockIdx.x < ATT_BLKS + MLP_BLKS) {
    // MLP layer 1 + SiLU: wave per (b,j)
    const int p = (blockIdx.x - ATT_BLKS) * 4 + wv;
    const int b = p >> 9, j = p & 511;
    const float4* a4 = (const float4*)(xp + (size_t)b * D);
    const float4* w4 = (const float4*)(w1 + (size_t)j * D);
    float acc = 0.f;
#pragma unroll
    for (int q = 0; q < 4; ++q) {
      float4 av = a4[q * 64 + lane];
      float4 wvv = w4[q * 64 + lane];
      acc += av.x * wvv.x + av.y * wvv.y + av.z * wvv.z + av.w * wvv.w;
    }
    acc = waveReduceSum(acc);
    if (lane == 0) {
      float z = acc + b1[j];
      h[(size_t)b * HID + j] = z / (1.0f + expf(-z)); // silu
    }
  } else {
    // cosine sims: wave per b
    const int b = (blockIdx.x - ATT_BLKS - MLP_BLKS) * 4 + wv;
    float xx = 0.f, d0 = 0.f, d1 = 0.f, n0 = 0.f, n1 = 0.f;
#pragma unroll
    for (int k = 0; k < 16; ++k) {
      int d = lane + k * 64;
      float v = xp[(size_t)b * D + d];
      float a = mk0[d];
      float c = mk1[d];
      xx += v * v;
      d0 += v * a;
      d1 += v * c;
      n0 += a * a;
      n1 += c * c;
    }
    xx = waveReduceSum(xx);
    d0 = waveReduceSum(d0);
    d1 = waveReduceSum(d1);
    n0 = waveReduceSum(n0);
    n1 = waveReduceSum(n1);
    if (lane == 0) {
      float xn = sqrtf(xx);
      sims[b * 2 + 0] = d0 / fmaxf(xn * sqrtf(n0), 1e-8f);
      sims[b * 2 + 1] = d1 / fmaxf(xn * sqrtf(n1), 1e-8f);
    }
  }
}

// ---- 5. softmax(64)+att@val, h@w2, concat gate, change-detector scalar ----
__global__ __launch_bounds__(256) void k_final(
    const float* __restrict__ h, const float* __restrict__ w2,
    const float* __restrict__ b2, const float* __restrict__ logit,
    const float* __restrict__ val, const float* __restrict__ cw,
    const float* __restrict__ cb, const float* __restrict__ sims,
    const float* __restrict__ thr, float* __restrict__ out) {
  const int b = blockIdx.x, tid = threadIdx.x, lane = tid & 63, wv = tid >> 6;
  __shared__ float s_red[4];
  __shared__ float s_mem;
  float acc = h[(size_t)b * HID + tid] * w2[tid] +
              h[(size_t)b * HID + 256 + tid] * w2[256 + tid];
  acc = waveReduceSum(acc);
  if (lane == 0) s_red[wv] = acc;
  if (wv == 0) { // wave 0 = 64 lanes = MEM
    float l = logit[b * MEM + lane];
    float mx = l;
#pragma unroll
    for (int m = 32; m; m >>= 1) mx = fmaxf(mx, __shfl_xor(mx, m, 64));
    float ex = expf(l - mx);
    float sm = waveReduceSum(ex);
    float mv = waveReduceSum((ex / sm) * val[lane]);
    if (lane == 0) s_mem = mv;
  }
  __syncthreads();
  if (tid == 0) {
    float mlp = s_red[0] + s_red[1] + s_red[2] + s_red[3] + b2[0];
    out[B + b] = cw[0] * s_mem + cw[1] * mlp + cb[0];
    int best = (sims[b * 2 + 1] > sims[b * 2 + 0]) ? 1 : 0;
    int changed;
    if (b == 0) {
      changed = 1;
    } else {
      int prev = (sims[(b - 1) * 2 + 1] > sims[(b - 1) * 2 + 0]) ? 1 : 0;
      changed = (best != prev);
    }
    out[b] = ((changed ? 1.0f : 0.0f) > thr[0]) ? 1.0f : 0.0f;
  }
}

extern "C" void kernel_launch(void* const* d_in, const int* in_sizes, int n_in,
                              void* d_out, int out_size, void* d_ws,
                              size_t ws_size, hipStream_t stream) {
  const float* x = (const float*)d_in[0];
  const float* mk0 = (const float*)d_in[1];
  const float* mk1 = (const float*)d_in[2];
  const float* key = (const float*)d_in[3];
  const float* val = (const float*)d_in[4];
  const float* w1 = (const float*)d_in[5];
  const float* b1 = (const float*)d_in[6];
  const float* w2 = (const float*)d_in[7];
  const float* b2 = (const float*)d_in[8];
  const float* cw = (const float*)d_in[9];
  const float* cb = (const float*)d_in[10];
  const float* xaw = (const float*)d_in[11];
  const float* xab = (const float*)d_in[12];
  const float* thr = (const float*)d_in[13];
  float* out = (float*)d_out;
  float* ws = (float*)d_ws;

  float* part = ws + OFF_PART;
  float* xm = ws + OFF_XM;
  float* xp = ws + OFF_XP;
  float* h = ws + OFF_H;
  float* lg = ws + OFF_LG;
  float* sims = ws + OFF_SIMS;

  k_partial<<<dim3(NCH, B), 256, 0, stream>>>(x, part);
  k_mean<<<B, 256, 0, stream>>>(part, xm);
  k_xp<<<(B * D) / 4, 256, 0, stream>>>(xm, xaw, xab, xp);
  k_fused<<<ATT_BLKS + MLP_BLKS + STATS_BLKS, 256, 0, stream>>>(
      xp, key, lg, w1, b1, h, mk0, mk1, sims);
  k_final<<<B, 256, 0, stream>>>(h, w2, b2, lg, val, cw, cb, sims, thr, out);
}